// Round 1
// 238.498 us; speedup vs baseline: 1.0082x; 1.0082x over previous
//
#include <hip/hip_runtime.h>

// DynamicConv2d: GAP->MLP->softmax routing, Wdyn = sum_k a_k * bank_k,
// then per-sample 3x3 conv (pad 1) = per-sample GEMM M=256,N=3136,K=1152.
// R6: k_conv rewritten as the 256x256 8-phase schedule (T3+T4 counted vmcnt,
// T5 setprio, T2 chunk-XOR swizzle kept) + sample->XCD affinity swizzle (T1).
// BM=256 = full COUT (A read once per block), BN=256 (13 chunks), BK=64,
// 512 thr / 8 waves (2Mx4N), 128 KiB double-buffered LDS via dynamic shared.
// Aux passes byte-identical to R5.

#define CIN    128
#define COUT   256
#define KEXP   8
#define HIDDEN 32
#define B_     32
#define H_     56
#define W_     56
#define HW     3136
#define HP     58      // 1 + 56 + 1 halo rows
#define WP     58      // 1 + 56 + 1 halo cols
#define KK     1152    // 9 * 128, order (kh*3+kw)*128 + cin

typedef float  v4f  __attribute__((ext_vector_type(4)));
typedef __bf16 v8bf __attribute__((ext_vector_type(8)));

__device__ __forceinline__ unsigned short f2bf(float x) {
  unsigned int u = __float_as_uint(x);
  u += 0x7fff + ((u >> 16) & 1);          // RNE
  return (unsigned short)(u >> 16);
}

// 16B-per-lane async global->LDS. LDS dest is wave-uniform base + lane*16.
__device__ __forceinline__ void gl_lds16(const void* g, void* lds) {
  __builtin_amdgcn_global_load_lds(
      (__attribute__((address_space(1))) void*)(unsigned long long)(g),
      (__attribute__((address_space(3))) void*)(lds),
      16, 0, 0);
}

// ---------------------------------------------------------------------------
// Pass 1 (v4): x (NCHW f32) -> xp_t (padded NHWC bf16, WP=58) + GAP partials
// to gpart[h][b][c] (no atomics). Blocks also zero their own halo cells.
// ---------------------------------------------------------------------------
__global__ __launch_bounds__(256) void k_xpose(const float* __restrict__ x,
                                               unsigned short* __restrict__ xpt,
                                               float* __restrict__ gpart) {
  const int h = blockIdx.x, b = blockIdx.y, tid = threadIdx.x;
  __shared__ float tf[56 * 129];      // 28.9 KB
  __shared__ float gp[256];
  const float4* xr4 = (const float4*)x + (size_t)b * CIN * 784;  // 784=3136/4

#pragma unroll
  for (int it = 0; it < 7; ++it) {    // 1792 float4 = 128c * 14wq
    int idx = it * 256 + tid;
    int c  = idx / 14;
    int wq = idx - c * 14;
    float4 q = xr4[(size_t)c * 784 + h * 14 + wq];
    int w0 = wq * 4;
    tf[(w0 + 0) * 129 + c] = q.x;
    tf[(w0 + 1) * 129 + c] = q.y;
    tf[(w0 + 2) * 129 + c] = q.z;
    tf[(w0 + 3) * 129 + c] = q.w;
  }
  __syncthreads();

  {                                   // GAP partial: 256 threads, 28 reads each
    int c = tid & 127, half = tid >> 7;
    float s = 0.f;
#pragma unroll
    for (int w = half * 28; w < half * 28 + 28; ++w) s += tf[w * 129 + c];
    gp[tid] = s;
  }

#pragma unroll
  for (int it = 0; it < 7; ++it) {    // 1792 ushort4 stores = 56w * 32 c-quads
    int idx = it * 256 + tid;
    int w  = idx >> 5;                // [0,56)
    int c4 = (idx & 31) << 2;         // [0,128) step 4
    ushort4 o;
    o.x = f2bf(tf[w * 129 + c4 + 0]);
    o.y = f2bf(tf[w * 129 + c4 + 1]);
    o.z = f2bf(tf[w * 129 + c4 + 2]);
    o.w = f2bf(tf[w * 129 + c4 + 3]);
    *(ushort4*)(xpt + ((size_t)(b * HP + (h + 1)) * WP + (w + 1)) * CIN + c4) = o;
  }

  // halo columns 0 and 57 of this image row
  if (tid < 128) {
    size_t rb = (size_t)(b * HP + (h + 1)) * WP * CIN;
    xpt[rb + tid] = 0;
    xpt[rb + 57 * CIN + tid] = 0;
  }
  // halo rows 0 and 57 (full 58*128 ushorts each)
  if (h == 0 || h == 55) {
    int hr = (h == 0) ? 0 : 57;
    size_t rb = (size_t)(b * HP + hr) * WP * CIN;
    ushort4 z; z.x = z.y = z.z = z.w = 0;
    for (int i = tid; i < 1856; i += 256)
      *(ushort4*)(xpt + rb + i * 4) = z;
  }

  __syncthreads();
  if (tid < 128)
    gpart[((size_t)h * B_ + b) * CIN + tid] =
        (gp[tid] + gp[tid + 128]) * (1.0f / 3136.0f);
}

// ---------------------------------------------------------------------------
// Pass 2 (v2): reduce gpart -> v (in LDS), then MLP + softmax. grid=32,
// block=128.
// ---------------------------------------------------------------------------
__global__ void k_mlp(const float* __restrict__ gpart, const float* __restrict__ fc1w,
                      const float* __restrict__ fc1b, const float* __restrict__ fc2w,
                      const float* __restrict__ fc2b, float* __restrict__ aout) {
  const int b = blockIdx.x, t = threadIdx.x;
  __shared__ float vS[CIN];
  __shared__ float hid[HIDDEN];
  __shared__ float lg[KEXP];
  {
    float s = 0.f;
    for (int h = 0; h < H_; ++h) s += gpart[((size_t)h * B_ + b) * CIN + t];
    vS[t] = s;
  }
  __syncthreads();
  if (t < HIDDEN) {
    float s = fc1b[t];
    const float* wr = fc1w + t * CIN;
    for (int c = 0; c < CIN; ++c) s += vS[c] * wr[c];
    hid[t] = fmaxf(s, 0.f);
  }
  __syncthreads();
  if (t < KEXP) {
    float s = fc2b[t];
    const float* wr = fc2w + t * HIDDEN;
    for (int j = 0; j < HIDDEN; ++j) s += hid[j] * wr[j];
    lg[t] = s;
  }
  __syncthreads();
  if (t == 0) {
    float m = lg[0];
    for (int k = 1; k < KEXP; ++k) m = fmaxf(m, lg[k]);
    float e[KEXP], den = 0.f;
    for (int k = 0; k < KEXP; ++k) { e[k] = expf(lg[k] - m); den += e[k]; }
    float inv = 1.0f / den;
    for (int k = 0; k < KEXP; ++k) aout[b * KEXP + k] = e[k] * inv;
  }
}

// ---------------------------------------------------------------------------
// Pass 3 (v3): Wdyn[b][cout][kk] bf16, kk = khw*128 + cin. One block of 512
// threads per cout. Stride-9 LDS reads = 2/bank = free; coalesced stores.
// ---------------------------------------------------------------------------
__global__ __launch_bounds__(512) void k_wdyn(const float* __restrict__ aout,
                                              const float* __restrict__ bank,
                                              unsigned short* __restrict__ wdyn) {
  const int cout = blockIdx.x, tid = threadIdx.x;
  __shared__ float4 bS4[KEXP * 288];          // 36 KB
  __shared__ float aS[B_ * KEXP];             // 256 routing coeffs

  for (int idx = tid; idx < KEXP * 288; idx += 512) {
    int k = idx / 288, r = idx - k * 288;
    bS4[idx] = ((const float4*)(bank + (size_t)(k * COUT + cout) * KK))[r];
  }
  if (tid < 256) aS[tid] = aout[tid];
  __syncthreads();

  const float* bS = (const float*)bS4;
  const int lane_kk = tid & 63;
  const int sg = tid >> 6;                    // 8 groups of 4 samples
  float areg[4][KEXP];
#pragma unroll
  for (int bi = 0; bi < 4; ++bi)
#pragma unroll
    for (int k = 0; k < KEXP; ++k) areg[bi][k] = aS[(sg * 4 + bi) * KEXP + k];

  for (int it = 0; it < 18; ++it) {
    int kk  = it * 64 + lane_kk;              // [0,1152)
    int khw = kk >> 7, cin = kk & 127;
    int e   = cin * 9 + khw;
    float vv[KEXP];
#pragma unroll
    for (int k = 0; k < KEXP; ++k) vv[k] = bS[k * KK + e];
#pragma unroll
    for (int bi = 0; bi < 4; ++bi) {
      float s = 0.f;
#pragma unroll
      for (int k = 0; k < KEXP; ++k) s += areg[bi][k] * vv[k];
      wdyn[(size_t)((sg * 4 + bi) * COUT + cout) * KK + kk] = f2bf(s);
    }
  }
}

// ---------------------------------------------------------------------------
// Pass 4 (R6): 256x256 8-phase MFMA GEMM per sample.
//   A = Wdyn[b] (256 couts x 1152), B = im2col(xpt[b]) (pixels x 1152).
//   512 threads = 8 waves (2M x 4N); wave tile 128 x 64; acc[8][4] f32x4.
//   LDS: 2 buffers x (A 32KB + B 32KB) = 128 KiB, chunk-XOR swizzled.
//   Per K-tile (64k): 4 half-tiles, each staged by 2 gl_lds16/thread.
//   Counted vmcnt(2) at the two switch phases only; vmcnt(0) only at prologue
//   and the final tile. setprio(1) around each 16-MFMA cluster.
// ---------------------------------------------------------------------------
#define BARX()   asm volatile("s_barrier" ::: "memory")
#define WAITV2() asm volatile("s_waitcnt vmcnt(2)" ::: "memory")
#define WAITV0() asm volatile("s_waitcnt vmcnt(0)" ::: "memory")

__device__ __forceinline__ void stage_a(const unsigned short* wb, unsigned short* Abuf,
                                        int hf, int ad, const int (&aoffj)[2], int wv) {
  const unsigned short* s = wb + hf * 128 * KK + ad;
  unsigned short* d = Abuf + hf * 8192;
  gl_lds16(s + aoffj[0], d + (wv * 64) * 8);
  gl_lds16(s + aoffj[1], d + (512 + wv * 64) * 8);
}

__device__ __forceinline__ void stage_b(const unsigned short* xb, unsigned short* Bbuf,
                                        int hf, int bd, const int (&boffj)[2][2], int wv) {
  unsigned short* d = Bbuf + hf * 8192;
  gl_lds16(xb + boffj[0][hf] + bd, d + (wv * 64) * 8);
  gl_lds16(xb + boffj[1][hf] + bd, d + (512 + wv * 64) * 8);
}

template <int MH, int NH>
__device__ __forceinline__ void load_quad(const unsigned short* Ab, const unsigned short* Bb,
                                          int abase, int bbase, int pA, int pB,
                                          v8bf (&af)[4][2], v8bf (&bv)[2][2]) {
#pragma unroll
  for (int mi = 0; mi < 4; ++mi) {
    int r = abase + (MH * 4 + mi) * 1024;
    af[mi][0] = *(const v8bf*)(Ab + r + pA);
    af[mi][1] = *(const v8bf*)(Ab + r + pB);
  }
#pragma unroll
  for (int ni = 0; ni < 2; ++ni) {
    int r = bbase + (NH * 2 + ni) * 1024;
    bv[ni][0] = *(const v8bf*)(Bb + r + pA);
    bv[ni][1] = *(const v8bf*)(Bb + r + pB);
  }
}

template <int MH, int NH>
__device__ __forceinline__ void mfma_quad(v8bf (&af)[4][2], v8bf (&bv)[2][2],
                                          v4f (&acc)[8][4]) {
  __builtin_amdgcn_s_setprio(1);
#pragma unroll
  for (int mi = 0; mi < 4; ++mi)
#pragma unroll
    for (int ni = 0; ni < 2; ++ni) {
      v4f& a = acc[MH * 4 + mi][NH * 2 + ni];
      a = __builtin_amdgcn_mfma_f32_16x16x32_bf16(af[mi][0], bv[ni][0], a, 0, 0, 0);
      a = __builtin_amdgcn_mfma_f32_16x16x32_bf16(af[mi][1], bv[ni][1], a, 0, 0, 0);
    }
  __builtin_amdgcn_s_setprio(0);
}

__global__ __launch_bounds__(512, 2) void k_conv256(const unsigned short* __restrict__ wdyn,
                                                    const unsigned short* __restrict__ xpt,
                                                    float* __restrict__ out) {
  extern __shared__ unsigned short sh[];
  unsigned short* As = sh;             // [2][16384] ushorts (64 KB)
  unsigned short* Bs = sh + 32768;     // [2][16384] ushorts (64 KB)

  // T1: sample->XCD affinity. 416 = 8 XCDs * 52; XCD x owns samples 4x..4x+3,
  // sample-major so one sample's 13 chunks co-run on one XCD (wdyn[b] L2-hot).
  const int id  = blockIdx.x;
  const int xcd = id & 7, idx = id >> 3;         // 52 blocks per XCD
  const int b   = xcd * 4 + idx / 13;
  const int ch  = idx - (idx / 13) * 13;         // 13 pixel chunks of 256
  const int p0  = ch << 8;

  const int tid = threadIdx.x;
  const int wv = tid >> 6, l = tid & 63;
  const int q4 = l >> 4, l15 = l & 15;
  const int wr = wv >> 2, wc = wv & 3;           // 2M x 4N wave grid

  const unsigned short* wb = wdyn + (size_t)b * COUT * KK;
  const unsigned short* xb = xpt + (size_t)b * HP * WP * CIN;

  // Per-lane staging source offsets (ushort units), K-tile-invariant.
  int aoffj[2];
  int boffj[2][2];
#pragma unroll
  for (int j = 0; j < 2; ++j) {
    int row0 = j * 64 + (tid >> 3);              // [0,128) row within half-tile
    int c = (tid & 7) ^ (row0 & 7);              // pre-swizzled logical chunk
    aoffj[j] = row0 * KK + c * 8;
#pragma unroll
    for (int hf = 0; hf < 2; ++hf) {
      int p = p0 + hf * 128 + row0;
      p = p > 3135 ? 3135 : p;                   // clamp (tail chunk)
      int ph = p / 56, pw = p - ph * 56;
      boffj[j][hf] = (ph * WP + pw) * CIN + c * 8;
    }
  }

  // LDS read bases (ushort units).
  const int abase = (wr * 128 + l15) * 64;
  const int bbase = (wc * 64 + l15) * 64;
  const int s7 = l15 & 7;
  const int pA = (q4 ^ s7) * 8;                  // k-slice 0 phys chunk
  const int pB = ((q4 + 4) ^ s7) * 8;            // k-slice 1 phys chunk

  v4f acc[8][4];
#pragma unroll
  for (int m = 0; m < 8; ++m)
#pragma unroll
    for (int n = 0; n < 4; ++n)
#pragma unroll
      for (int rr = 0; rr < 4; ++rr) acc[m][n][rr] = 0.f;

  unsigned short* A0 = As;           unsigned short* B0 = Bs;
  unsigned short* A1 = As + 16384;   unsigned short* B1 = Bs + 16384;

  // Prologue: stage K-tile 0 (khw=0 -> bd=0, ad=0) into buf0, full drain once.
  stage_a(wb, A0, 0, 0, aoffj, wv);
  stage_a(wb, A0, 1, 0, aoffj, wv);
  stage_b(xb, B0, 0, 0, boffj, wv);
  stage_b(xb, B0, 1, 0, boffj, wv);
  WAITV0();
  BARX();

  v8bf af[4][2], bv[2][2];
  int kh = 0, kw = 0;                            // khw = i for tiles 2i, 2i+1
  for (int i = 0; i < 9; ++i) {
    int kw2 = kw + 1, kh2 = kh;
    if (kw2 == 3) { kw2 = 0; kh2 = kh + 1; }     // khw = i+1 (next even tile)
    const int adO = (2 * i + 1) * 64;            // A k-offset, odd tile
    const int adN = (2 * i + 2) * 64;            // A k-offset, next even tile
    const int bdO = (kh * WP + kw) * CIN + 64;   // B disp, odd tile (cinb=64)
    const int bdN = (kh2 * WP + kw2) * CIN;      // B disp, next even (cinb=0)
    const bool lastI = (i == 8);

    // ---- phases 0-3: compute buf0 (kt=2i), stage kt=2i+1 -> buf1 ----
    // phase 0 (switch: buf0's 8 loads are the oldest outstanding)
    stage_a(wb, A1, 0, adO, aoffj, wv);
    WAITV2();
    BARX();
    load_quad<0, 0>(A0, B0, abase, bbase, pA, pB, af, bv);
    mfma_quad<0, 0>(af, bv, acc);
    BARX();
    // phase 1
    load_quad<0, 1>(A0, B0, abase, bbase, pA, pB, af, bv);
    stage_a(wb, A1, 1, adO, aoffj, wv);
    BARX();
    mfma_quad<0, 1>(af, bv, acc);
    BARX();
    // phase 2
    load_quad<1, 0>(A0, B0, abase, bbase, pA, pB, af, bv);
    stage_b(xb, B1, 0, bdO, boffj, wv);
    BARX();
    mfma_quad<1, 0>(af, bv, acc);
    BARX();
    // phase 3
    load_quad<1, 1>(A0, B0, abase, bbase, pA, pB, af, bv);
    stage_b(xb, B1, 1, bdO, boffj, wv);
    BARX();
    mfma_quad<1, 1>(af, bv, acc);
    BARX();

    // ---- phases 4-7: compute buf1 (kt=2i+1), stage kt=2i+2 -> buf0 ----
    // phase 4 (switch: buf1's 8 loads must drain)
    if (!lastI) {
      stage_a(wb, A0, 0, adN, aoffj, wv);
      WAITV2();
    } else {
      WAITV0();
    }
    BARX();
    load_quad<0, 0>(A1, B1, abase, bbase, pA, pB, af, bv);
    mfma_quad<0, 0>(af, bv, acc);
    BARX();
    // phase 5
    load_quad<0, 1>(A1, B1, abase, bbase, pA, pB, af, bv);
    if (!lastI) stage_a(wb, A0, 1, adN, aoffj, wv);
    BARX();
    mfma_quad<0, 1>(af, bv, acc);
    BARX();
    // phase 6
    load_quad<1, 0>(A1, B1, abase, bbase, pA, pB, af, bv);
    if (!lastI) stage_b(xb, B0, 0, bdN, boffj, wv);
    BARX();
    mfma_quad<1, 0>(af, bv, acc);
    BARX();
    // phase 7
    load_quad<1, 1>(A1, B1, abase, bbase, pA, pB, af, bv);
    if (!lastI) stage_b(xb, B0, 1, bdN, boffj, wv);
    BARX();
    mfma_quad<1, 1>(af, bv, acc);
    BARX();

    kh = kh2; kw = kw2;
  }

  // Epilogue: D col = pixel (lane&15), D rows = cout = wr*128 + mf*16 + 4q + rr.
#pragma unroll
  for (int mf = 0; mf < 8; ++mf) {
    int cout = wr * 128 + mf * 16 + 4 * q4;
#pragma unroll
    for (int nf = 0; nf < 4; ++nf) {
      int p = p0 + wc * 64 + nf * 16 + l15;
      if (p < HW) {
        float* op = out + (size_t)(b * COUT + cout) * HW + p;
#pragma unroll
        for (int rr = 0; rr < 4; ++rr) op[(size_t)rr * HW] = acc[mf][nf][rr];
      }
    }
  }
}

// ---------------------------------------------------------------------------
// Workspace layout (~48.5 MB, all regions fully written before read):
//   [0, 917504)            gpart f32 [56][32][128]
//   [1 MB, +1024)          a f32 [32][8]
//   [2 MB, +18874368)      Wdyn bf16 [b][cout][1152]
//   [2MB+18874368, +27553792)  xp_t bf16 [b][58][58][128]
// ---------------------------------------------------------------------------
extern "C" void kernel_launch(void* const* d_in, const int* in_sizes, int n_in,
                              void* d_out, int out_size, void* d_ws, size_t ws_size,
                              hipStream_t stream) {
  const float* x    = (const float*)d_in[0];
  const float* bank = (const float*)d_in[1];
  const float* fc1w = (const float*)d_in[2];
  const float* fc1b = (const float*)d_in[3];
  const float* fc2w = (const float*)d_in[4];
  const float* fc2b = (const float*)d_in[5];
  float* out = (float*)d_out;

  char* ws = (char*)d_ws;
  float* gpart = (float*)(ws + 0);
  float* aout  = (float*)(ws + (1u << 20));
  unsigned short* wdyn = (unsigned short*)(ws + (2u << 20));
  unsigned short* xpt  = (unsigned short*)(ws + (2u << 20) + 18874368);

  static bool attr_done = false;
  if (!attr_done) {
    (void)hipFuncSetAttribute((const void*)k_conv256,
                              hipFuncAttributeMaxDynamicSharedMemorySize, 131072);
    attr_done = true;
  }

  k_xpose<<<dim3(H_, B_), 256, 0, stream>>>(x, xpt, gpart);
  k_mlp<<<dim3(B_), 128, 0, stream>>>(gpart, fc1w, fc1b, fc2w, fc2b, aout);
  k_wdyn<<<dim3(COUT), 512, 0, stream>>>(aout, bank, wdyn);
  k_conv256<<<dim3(416), 512, 131072, stream>>>(wdyn, xpt, out);
}

// Round 3
// 228.823 us; speedup vs baseline: 1.0509x; 1.0423x over previous
//
#include <hip/hip_runtime.h>

// DynamicConv2d: GAP->MLP->softmax routing, Wdyn = sum_k a_k * bank_k,
// then per-sample 3x3 conv (pad 1) = per-sample GEMM M=256,N=3136,K=1152.
// R8: R7's fragment-reuse schedule with the switch-phase race fixed.
// R7 read the incoming buffer BEFORE the vmcnt wait+barrier (NaN). R8
// restores R6's proven P0 order: stage -> WAITV2/WAITV0 -> BARX -> ds_read
// -> MFMA. Zig-zag quadrant order (0,0)->(0,1)->(1,1)->(1,0) keeps af
// cached across MH-pairs and bv0/bv1 live across the K-tile:
// ds_read_b128 per K-tile per wave = 24 (R6: 48). Aux passes unchanged.

#define CIN    128
#define COUT   256
#define KEXP   8
#define HIDDEN 32
#define B_     32
#define H_     56
#define W_     56
#define HW     3136
#define HP     58      // 1 + 56 + 1 halo rows
#define WP     58      // 1 + 56 + 1 halo cols
#define KK     1152    // 9 * 128, order (kh*3+kw)*128 + cin

typedef float  v4f  __attribute__((ext_vector_type(4)));
typedef __bf16 v8bf __attribute__((ext_vector_type(8)));

__device__ __forceinline__ unsigned short f2bf(float x) {
  unsigned int u = __float_as_uint(x);
  u += 0x7fff + ((u >> 16) & 1);          // RNE
  return (unsigned short)(u >> 16);
}

// 16B-per-lane async global->LDS. LDS dest is wave-uniform base + lane*16.
__device__ __forceinline__ void gl_lds16(const void* g, void* lds) {
  __builtin_amdgcn_global_load_lds(
      (__attribute__((address_space(1))) void*)(unsigned long long)(g),
      (__attribute__((address_space(3))) void*)(lds),
      16, 0, 0);
}

// ---------------------------------------------------------------------------
// Pass 1 (v4): x (NCHW f32) -> xp_t (padded NHWC bf16, WP=58) + GAP partials
// to gpart[h][b][c] (no atomics). Blocks also zero their own halo cells.
// ---------------------------------------------------------------------------
__global__ __launch_bounds__(256) void k_xpose(const float* __restrict__ x,
                                               unsigned short* __restrict__ xpt,
                                               float* __restrict__ gpart) {
  const int h = blockIdx.x, b = blockIdx.y, tid = threadIdx.x;
  __shared__ float tf[56 * 129];      // 28.9 KB
  __shared__ float gp[256];
  const float4* xr4 = (const float4*)x + (size_t)b * CIN * 784;  // 784=3136/4

#pragma unroll
  for (int it = 0; it < 7; ++it) {    // 1792 float4 = 128c * 14wq
    int idx = it * 256 + tid;
    int c  = idx / 14;
    int wq = idx - c * 14;
    float4 q = xr4[(size_t)c * 784 + h * 14 + wq];
    int w0 = wq * 4;
    tf[(w0 + 0) * 129 + c] = q.x;
    tf[(w0 + 1) * 129 + c] = q.y;
    tf[(w0 + 2) * 129 + c] = q.z;
    tf[(w0 + 3) * 129 + c] = q.w;
  }
  __syncthreads();

  {                                   // GAP partial: 256 threads, 28 reads each
    int c = tid & 127, half = tid >> 7;
    float s = 0.f;
#pragma unroll
    for (int w = half * 28; w < half * 28 + 28; ++w) s += tf[w * 129 + c];
    gp[tid] = s;
  }

#pragma unroll
  for (int it = 0; it < 7; ++it) {    // 1792 ushort4 stores = 56w * 32 c-quads
    int idx = it * 256 + tid;
    int w  = idx >> 5;                // [0,56)
    int c4 = (idx & 31) << 2;         // [0,128) step 4
    ushort4 o;
    o.x = f2bf(tf[w * 129 + c4 + 0]);
    o.y = f2bf(tf[w * 129 + c4 + 1]);
    o.z = f2bf(tf[w * 129 + c4 + 2]);
    o.w = f2bf(tf[w * 129 + c4 + 3]);
    *(ushort4*)(xpt + ((size_t)(b * HP + (h + 1)) * WP + (w + 1)) * CIN + c4) = o;
  }

  // halo columns 0 and 57 of this image row
  if (tid < 128) {
    size_t rb = (size_t)(b * HP + (h + 1)) * WP * CIN;
    xpt[rb + tid] = 0;
    xpt[rb + 57 * CIN + tid] = 0;
  }
  // halo rows 0 and 57 (full 58*128 ushorts each)
  if (h == 0 || h == 55) {
    int hr = (h == 0) ? 0 : 57;
    size_t rb = (size_t)(b * HP + hr) * WP * CIN;
    ushort4 z; z.x = z.y = z.z = z.w = 0;
    for (int i = tid; i < 1856; i += 256)
      *(ushort4*)(xpt + rb + i * 4) = z;
  }

  __syncthreads();
  if (tid < 128)
    gpart[((size_t)h * B_ + b) * CIN + tid] =
        (gp[tid] + gp[tid + 128]) * (1.0f / 3136.0f);
}

// ---------------------------------------------------------------------------
// Pass 2 (v2): reduce gpart -> v (in LDS), then MLP + softmax. grid=32,
// block=128.
// ---------------------------------------------------------------------------
__global__ void k_mlp(const float* __restrict__ gpart, const float* __restrict__ fc1w,
                      const float* __restrict__ fc1b, const float* __restrict__ fc2w,
                      const float* __restrict__ fc2b, float* __restrict__ aout) {
  const int b = blockIdx.x, t = threadIdx.x;
  __shared__ float vS[CIN];
  __shared__ float hid[HIDDEN];
  __shared__ float lg[KEXP];
  {
    float s = 0.f;
    for (int h = 0; h < H_; ++h) s += gpart[((size_t)h * B_ + b) * CIN + t];
    vS[t] = s;
  }
  __syncthreads();
  if (t < HIDDEN) {
    float s = fc1b[t];
    const float* wr = fc1w + t * CIN;
    for (int c = 0; c < CIN; ++c) s += vS[c] * wr[c];
    hid[t] = fmaxf(s, 0.f);
  }
  __syncthreads();
  if (t < KEXP) {
    float s = fc2b[t];
    const float* wr = fc2w + t * HIDDEN;
    for (int j = 0; j < HIDDEN; ++j) s += hid[j] * wr[j];
    lg[t] = s;
  }
  __syncthreads();
  if (t == 0) {
    float m = lg[0];
    for (int k = 1; k < KEXP; ++k) m = fmaxf(m, lg[k]);
    float e[KEXP], den = 0.f;
    for (int k = 0; k < KEXP; ++k) { e[k] = expf(lg[k] - m); den += e[k]; }
    float inv = 1.0f / den;
    for (int k = 0; k < KEXP; ++k) aout[b * KEXP + k] = e[k] * inv;
  }
}

// ---------------------------------------------------------------------------
// Pass 3 (v3): Wdyn[b][cout][kk] bf16, kk = khw*128 + cin. One block of 512
// threads per cout. Stride-9 LDS reads = 2/bank = free; coalesced stores.
// ---------------------------------------------------------------------------
__global__ __launch_bounds__(512) void k_wdyn(const float* __restrict__ aout,
                                              const float* __restrict__ bank,
                                              unsigned short* __restrict__ wdyn) {
  const int cout = blockIdx.x, tid = threadIdx.x;
  __shared__ float4 bS4[KEXP * 288];          // 36 KB
  __shared__ float aS[B_ * KEXP];             // 256 routing coeffs

  for (int idx = tid; idx < KEXP * 288; idx += 512) {
    int k = idx / 288, r = idx - k * 288;
    bS4[idx] = ((const float4*)(bank + (size_t)(k * COUT + cout) * KK))[r];
  }
  if (tid < 256) aS[tid] = aout[tid];
  __syncthreads();

  const float* bS = (const float*)bS4;
  const int lane_kk = tid & 63;
  const int sg = tid >> 6;                    // 8 groups of 4 samples
  float areg[4][KEXP];
#pragma unroll
  for (int bi = 0; bi < 4; ++bi)
#pragma unroll
    for (int k = 0; k < KEXP; ++k) areg[bi][k] = aS[(sg * 4 + bi) * KEXP + k];

  for (int it = 0; it < 18; ++it) {
    int kk  = it * 64 + lane_kk;              // [0,1152)
    int khw = kk >> 7, cin = kk & 127;
    int e   = cin * 9 + khw;
    float vv[KEXP];
#pragma unroll
    for (int k = 0; k < KEXP; ++k) vv[k] = bS[k * KK + e];
#pragma unroll
    for (int bi = 0; bi < 4; ++bi) {
      float s = 0.f;
#pragma unroll
      for (int k = 0; k < KEXP; ++k) s += areg[bi][k] * vv[k];
      wdyn[(size_t)((sg * 4 + bi) * COUT + cout) * KK + kk] = f2bf(s);
    }
  }
}

// ---------------------------------------------------------------------------
// Pass 4 (R8): 256x256 8-phase MFMA GEMM per sample, fragment-reuse schedule.
//   Quadrant order per K-tile: (0,0)->(0,1)->(1,1)->(1,0); af cached across
//   MH-pairs, bv0/bv1 both live across the K-tile -> ds_read_b128 per K-tile
//   per wave = 24 (R6: 48). Switch phase P0 uses R6's proven ordering:
//   stage -> counted vmcnt -> barrier -> ds_read -> MFMA (reads of the
//   incoming buffer only after its staging loads are drained in ALL waves).
// ---------------------------------------------------------------------------
#define BARX()   asm volatile("s_barrier" ::: "memory")
#define WAITV2() asm volatile("s_waitcnt vmcnt(2)" ::: "memory")
#define WAITV0() asm volatile("s_waitcnt vmcnt(0)" ::: "memory")

__device__ __forceinline__ void stage_a(const unsigned short* wb, unsigned short* Abuf,
                                        int hf, int ad, const int (&aoffj)[2], int wv) {
  const unsigned short* s = wb + hf * 128 * KK + ad;
  unsigned short* d = Abuf + hf * 8192;
  gl_lds16(s + aoffj[0], d + (wv * 64) * 8);
  gl_lds16(s + aoffj[1], d + (512 + wv * 64) * 8);
}

__device__ __forceinline__ void stage_b(const unsigned short* xb, unsigned short* Bbuf,
                                        int hf, int bd, const int (&boffj)[2][2], int wv) {
  unsigned short* d = Bbuf + hf * 8192;
  gl_lds16(xb + boffj[0][hf] + bd, d + (wv * 64) * 8);
  gl_lds16(xb + boffj[1][hf] + bd, d + (512 + wv * 64) * 8);
}

template <int MH>
__device__ __forceinline__ void load_a(const unsigned short* Ab, int abase, int pA, int pB,
                                       v8bf (&af)[4][2]) {
#pragma unroll
  for (int mi = 0; mi < 4; ++mi) {
    int r = abase + (MH * 4 + mi) * 1024;
    af[mi][0] = *(const v8bf*)(Ab + r + pA);
    af[mi][1] = *(const v8bf*)(Ab + r + pB);
  }
}

template <int NH>
__device__ __forceinline__ void load_b(const unsigned short* Bb, int bbase, int pA, int pB,
                                       v8bf (&bv)[2][2]) {
#pragma unroll
  for (int ni = 0; ni < 2; ++ni) {
    int r = bbase + (NH * 2 + ni) * 1024;
    bv[ni][0] = *(const v8bf*)(Bb + r + pA);
    bv[ni][1] = *(const v8bf*)(Bb + r + pB);
  }
}

template <int MH, int NH>
__device__ __forceinline__ void mfma_q(v8bf (&af)[4][2], v8bf (&bv)[2][2],
                                       v4f (&acc)[8][4]) {
  __builtin_amdgcn_s_setprio(1);
#pragma unroll
  for (int mi = 0; mi < 4; ++mi)
#pragma unroll
    for (int ni = 0; ni < 2; ++ni) {
      v4f& a = acc[MH * 4 + mi][NH * 2 + ni];
      a = __builtin_amdgcn_mfma_f32_16x16x32_bf16(af[mi][0], bv[ni][0], a, 0, 0, 0);
      a = __builtin_amdgcn_mfma_f32_16x16x32_bf16(af[mi][1], bv[ni][1], a, 0, 0, 0);
    }
  __builtin_amdgcn_s_setprio(0);
}

__global__ __launch_bounds__(512, 2) void k_conv256(const unsigned short* __restrict__ wdyn,
                                                    const unsigned short* __restrict__ xpt,
                                                    float* __restrict__ out) {
  extern __shared__ unsigned short sh[];
  unsigned short* As = sh;             // [2][16384] ushorts (64 KB)
  unsigned short* Bs = sh + 32768;     // [2][16384] ushorts (64 KB)

  // T1: sample->XCD affinity. 416 = 8 XCDs * 52; XCD x owns samples 4x..4x+3,
  // sample-major so one sample's 13 chunks co-run on one XCD (wdyn[b] L2-hot).
  const int id  = blockIdx.x;
  const int xcd = id & 7, idx = id >> 3;         // 52 blocks per XCD
  const int b   = xcd * 4 + idx / 13;
  const int ch  = idx - (idx / 13) * 13;         // 13 pixel chunks of 256
  const int p0  = ch << 8;

  const int tid = threadIdx.x;
  const int wv = tid >> 6, l = tid & 63;
  const int q4 = l >> 4, l15 = l & 15;
  const int wr = wv >> 2, wc = wv & 3;           // 2M x 4N wave grid

  const unsigned short* wb = wdyn + (size_t)b * COUT * KK;
  const unsigned short* xb = xpt + (size_t)b * HP * WP * CIN;

  // Per-lane staging source offsets (ushort units), K-tile-invariant.
  int aoffj[2];
  int boffj[2][2];
#pragma unroll
  for (int j = 0; j < 2; ++j) {
    int row0 = j * 64 + (tid >> 3);              // [0,128) row within half-tile
    int c = (tid & 7) ^ (row0 & 7);              // pre-swizzled logical chunk
    aoffj[j] = row0 * KK + c * 8;
#pragma unroll
    for (int hf = 0; hf < 2; ++hf) {
      int p = p0 + hf * 128 + row0;
      p = p > 3135 ? 3135 : p;                   // clamp (tail chunk)
      int ph = p / 56, pw = p - ph * 56;
      boffj[j][hf] = (ph * WP + pw) * CIN + c * 8;
    }
  }

  // LDS read bases (ushort units).
  const int abase = (wr * 128 + l15) * 64;
  const int bbase = (wc * 64 + l15) * 64;
  const int s7 = l15 & 7;
  const int pA = (q4 ^ s7) * 8;                  // k-slice 0 phys chunk
  const int pB = ((q4 + 4) ^ s7) * 8;            // k-slice 1 phys chunk

  v4f acc[8][4];
#pragma unroll
  for (int m = 0; m < 8; ++m)
#pragma unroll
    for (int n = 0; n < 4; ++n)
#pragma unroll
      for (int rr = 0; rr < 4; ++rr) acc[m][n][rr] = 0.f;

  unsigned short* A0 = As;           unsigned short* B0 = Bs;
  unsigned short* A1 = As + 16384;   unsigned short* B1 = Bs + 16384;

  // Prologue: stage K-tile 0 (khw=0 -> bd=0, ad=0) into buf0, full drain once.
  stage_a(wb, A0, 0, 0, aoffj, wv);
  stage_a(wb, A0, 1, 0, aoffj, wv);
  stage_b(xb, B0, 0, 0, boffj, wv);
  stage_b(xb, B0, 1, 0, boffj, wv);
  WAITV0();
  BARX();

  v8bf afA[4][2], bv0[2][2], bv1[2][2];

  // One K-tile (4 phases) on (Ab,Bb); stage next tile into (An,Bn) when
  // doStage. Phase ds_reads: 12 / 4 / 8 / 0 b128.
  auto halftile = [&](const unsigned short* Ab, const unsigned short* Bb,
                      unsigned short* An, unsigned short* Bn,
                      int adS, int bdS, bool doStage) {
    // P0 (switch): stage A half0, counted wait, barrier, THEN read + mfma(0,0).
    // Reads of the incoming buffer must follow the wait+barrier (R7 bug).
    if (doStage) { stage_a(wb, An, 0, adS, aoffj, wv); WAITV2(); }
    else         { WAITV0(); }
    BARX();
    load_a<0>(Ab, abase, pA, pB, afA);
    load_b<0>(Bb, bbase, pA, pB, bv0);
    mfma_q<0, 0>(afA, bv0, acc);
    BARX();
    // P1: (0,1) — load bv1 only (af reused); stage A half 1.
    load_b<1>(Bb, bbase, pA, pB, bv1);
    if (doStage) stage_a(wb, An, 1, adS, aoffj, wv);
    BARX();
    mfma_q<0, 1>(afA, bv1, acc);
    BARX();
    // P2: (1,1) — load af(MH1) only (bv1 reused); stage B half 0.
    load_a<1>(Ab, abase, pA, pB, afA);
    if (doStage) stage_b(xb, Bn, 0, bdS, boffj, wv);
    BARX();
    mfma_q<1, 1>(afA, bv1, acc);
    BARX();
    // P3: (1,0) — no ds_reads (af, bv0 reused); stage B half 1.
    if (doStage) stage_b(xb, Bn, 1, bdS, boffj, wv);
    BARX();
    mfma_q<1, 0>(afA, bv0, acc);
    BARX();
  };

  int kh = 0, kw = 0;                            // khw = i for tiles 2i, 2i+1
  for (int i = 0; i < 9; ++i) {
    int kw2 = kw + 1, kh2 = kh;
    if (kw2 == 3) { kw2 = 0; kh2 = kh + 1; }     // khw = i+1 (next even tile)
    const int adO = (2 * i + 1) * 64;            // A k-offset, odd tile
    const int adN = (2 * i + 2) * 64;            // A k-offset, next even tile
    const int bdO = (kh * WP + kw) * CIN + 64;   // B disp, odd tile (cinb=64)
    const int bdN = (kh2 * WP + kw2) * CIN;      // B disp, next even (cinb=0)

    // compute buf0 (tile 2i), stage tile 2i+1 -> buf1
    halftile(A0, B0, A1, B1, adO, bdO, true);
    // compute buf1 (tile 2i+1), stage tile 2i+2 -> buf0 (not on last)
    halftile(A1, B1, A0, B0, adN, bdN, i != 8);

    kh = kh2; kw = kw2;
  }

  // Epilogue: D col = pixel (lane&15), D rows = cout = wr*128 + mf*16 + 4q + rr.
#pragma unroll
  for (int mf = 0; mf < 8; ++mf) {
    int cout = wr * 128 + mf * 16 + 4 * q4;
#pragma unroll
    for (int nf = 0; nf < 4; ++nf) {
      int p = p0 + wc * 64 + nf * 16 + l15;
      if (p < HW) {
        float* op = out + (size_t)(b * COUT + cout) * HW + p;
#pragma unroll
        for (int rr = 0; rr < 4; ++rr) op[(size_t)rr * HW] = acc[mf][nf][rr];
      }
    }
  }
}

// ---------------------------------------------------------------------------
// Workspace layout (~48.5 MB, all regions fully written before read):
//   [0, 917504)            gpart f32 [56][32][128]
//   [1 MB, +1024)          a f32 [32][8]
//   [2 MB, +18874368)      Wdyn bf16 [b][cout][1152]
//   [2MB+18874368, +27553792)  xp_t bf16 [b][58][58][128]
// ---------------------------------------------------------------------------
extern "C" void kernel_launch(void* const* d_in, const int* in_sizes, int n_in,
                              void* d_out, int out_size, void* d_ws, size_t ws_size,
                              hipStream_t stream) {
  const float* x    = (const float*)d_in[0];
  const float* bank = (const float*)d_in[1];
  const float* fc1w = (const float*)d_in[2];
  const float* fc1b = (const float*)d_in[3];
  const float* fc2w = (const float*)d_in[4];
  const float* fc2b = (const float*)d_in[5];
  float* out = (float*)d_out;

  char* ws = (char*)d_ws;
  float* gpart = (float*)(ws + 0);
  float* aout  = (float*)(ws + (1u << 20));
  unsigned short* wdyn = (unsigned short*)(ws + (2u << 20));
  unsigned short* xpt  = (unsigned short*)(ws + (2u << 20) + 18874368);

  static bool attr_done = false;
  if (!attr_done) {
    (void)hipFuncSetAttribute((const void*)k_conv256,
                              hipFuncAttributeMaxDynamicSharedMemorySize, 131072);
    attr_done = true;
  }

  k_xpose<<<dim3(H_, B_), 256, 0, stream>>>(x, xpt, gpart);
  k_mlp<<<dim3(B_), 128, 0, stream>>>(gpart, fc1w, fc1b, fc2w, fc2b, aout);
  k_wdyn<<<dim3(COUT), 512, 0, stream>>>(aout, bank, wdyn);
  k_conv256<<<dim3(416), 512, 131072, stream>>>(wdyn, xpt, out);
}

// Round 4
// 227.510 us; speedup vs baseline: 1.0569x; 1.0058x over previous
//
#include <hip/hip_runtime.h>

// DynamicConv2d: GAP->MLP->softmax routing, Wdyn = sum_k a_k * bank_k,
// then per-sample 3x3 conv (pad 1) = per-sample GEMM M=256,N=3136,K=1152.
// R9: k_conv256 phase-overlap fixes on top of R8 (per-tile serialization:
// measured 5270 cyc/tile = MFMA 2480 + LDS 2310 + barriers, nothing hidden).
//  (a) P0 quadrant split into 2x8 MFMA with af0 split-load (first wait 12->8
//      reads); (b) af(MH1) reload moved INTO P1's MFMA slot, pinned by
//      sched_barrier(0) (latency hides under mfma<0,1>, no reg-pressure
//      growth); (c) both B-half stages hoisted to P2 (~1250 cyc before the
//      switch vmcnt wait, was ~600); (d) P2/P3 compute merged, 5 barriers
//      per tile (was 8). Per-acc MFMA order unchanged (bitwise-identical).
// Aux passes unchanged.

#define CIN    128
#define COUT   256
#define KEXP   8
#define HIDDEN 32
#define B_     32
#define H_     56
#define W_     56
#define HW     3136
#define HP     58      // 1 + 56 + 1 halo rows
#define WP     58      // 1 + 56 + 1 halo cols
#define KK     1152    // 9 * 128, order (kh*3+kw)*128 + cin

typedef float  v4f  __attribute__((ext_vector_type(4)));
typedef __bf16 v8bf __attribute__((ext_vector_type(8)));

__device__ __forceinline__ unsigned short f2bf(float x) {
  unsigned int u = __float_as_uint(x);
  u += 0x7fff + ((u >> 16) & 1);          // RNE
  return (unsigned short)(u >> 16);
}

// 16B-per-lane async global->LDS. LDS dest is wave-uniform base + lane*16.
__device__ __forceinline__ void gl_lds16(const void* g, void* lds) {
  __builtin_amdgcn_global_load_lds(
      (__attribute__((address_space(1))) void*)(unsigned long long)(g),
      (__attribute__((address_space(3))) void*)(lds),
      16, 0, 0);
}

// ---------------------------------------------------------------------------
// Pass 1 (v4): x (NCHW f32) -> xp_t (padded NHWC bf16, WP=58) + GAP partials
// to gpart[h][b][c] (no atomics). Blocks also zero their own halo cells.
// ---------------------------------------------------------------------------
__global__ __launch_bounds__(256) void k_xpose(const float* __restrict__ x,
                                               unsigned short* __restrict__ xpt,
                                               float* __restrict__ gpart) {
  const int h = blockIdx.x, b = blockIdx.y, tid = threadIdx.x;
  __shared__ float tf[56 * 129];      // 28.9 KB
  __shared__ float gp[256];
  const float4* xr4 = (const float4*)x + (size_t)b * CIN * 784;  // 784=3136/4

#pragma unroll
  for (int it = 0; it < 7; ++it) {    // 1792 float4 = 128c * 14wq
    int idx = it * 256 + tid;
    int c  = idx / 14;
    int wq = idx - c * 14;
    float4 q = xr4[(size_t)c * 784 + h * 14 + wq];
    int w0 = wq * 4;
    tf[(w0 + 0) * 129 + c] = q.x;
    tf[(w0 + 1) * 129 + c] = q.y;
    tf[(w0 + 2) * 129 + c] = q.z;
    tf[(w0 + 3) * 129 + c] = q.w;
  }
  __syncthreads();

  {                                   // GAP partial: 256 threads, 28 reads each
    int c = tid & 127, half = tid >> 7;
    float s = 0.f;
#pragma unroll
    for (int w = half * 28; w < half * 28 + 28; ++w) s += tf[w * 129 + c];
    gp[tid] = s;
  }

#pragma unroll
  for (int it = 0; it < 7; ++it) {    // 1792 ushort4 stores = 56w * 32 c-quads
    int idx = it * 256 + tid;
    int w  = idx >> 5;                // [0,56)
    int c4 = (idx & 31) << 2;         // [0,128) step 4
    ushort4 o;
    o.x = f2bf(tf[w * 129 + c4 + 0]);
    o.y = f2bf(tf[w * 129 + c4 + 1]);
    o.z = f2bf(tf[w * 129 + c4 + 2]);
    o.w = f2bf(tf[w * 129 + c4 + 3]);
    *(ushort4*)(xpt + ((size_t)(b * HP + (h + 1)) * WP + (w + 1)) * CIN + c4) = o;
  }

  // halo columns 0 and 57 of this image row
  if (tid < 128) {
    size_t rb = (size_t)(b * HP + (h + 1)) * WP * CIN;
    xpt[rb + tid] = 0;
    xpt[rb + 57 * CIN + tid] = 0;
  }
  // halo rows 0 and 57 (full 58*128 ushorts each)
  if (h == 0 || h == 55) {
    int hr = (h == 0) ? 0 : 57;
    size_t rb = (size_t)(b * HP + hr) * WP * CIN;
    ushort4 z; z.x = z.y = z.z = z.w = 0;
    for (int i = tid; i < 1856; i += 256)
      *(ushort4*)(xpt + rb + i * 4) = z;
  }

  __syncthreads();
  if (tid < 128)
    gpart[((size_t)h * B_ + b) * CIN + tid] =
        (gp[tid] + gp[tid + 128]) * (1.0f / 3136.0f);
}

// ---------------------------------------------------------------------------
// Pass 2 (v2): reduce gpart -> v (in LDS), then MLP + softmax. grid=32,
// block=128.
// ---------------------------------------------------------------------------
__global__ void k_mlp(const float* __restrict__ gpart, const float* __restrict__ fc1w,
                      const float* __restrict__ fc1b, const float* __restrict__ fc2w,
                      const float* __restrict__ fc2b, float* __restrict__ aout) {
  const int b = blockIdx.x, t = threadIdx.x;
  __shared__ float vS[CIN];
  __shared__ float hid[HIDDEN];
  __shared__ float lg[KEXP];
  {
    float s = 0.f;
    for (int h = 0; h < H_; ++h) s += gpart[((size_t)h * B_ + b) * CIN + t];
    vS[t] = s;
  }
  __syncthreads();
  if (t < HIDDEN) {
    float s = fc1b[t];
    const float* wr = fc1w + t * CIN;
    for (int c = 0; c < CIN; ++c) s += vS[c] * wr[c];
    hid[t] = fmaxf(s, 0.f);
  }
  __syncthreads();
  if (t < KEXP) {
    float s = fc2b[t];
    const float* wr = fc2w + t * HIDDEN;
    for (int j = 0; j < HIDDEN; ++j) s += hid[j] * wr[j];
    lg[t] = s;
  }
  __syncthreads();
  if (t == 0) {
    float m = lg[0];
    for (int k = 1; k < KEXP; ++k) m = fmaxf(m, lg[k]);
    float e[KEXP], den = 0.f;
    for (int k = 0; k < KEXP; ++k) { e[k] = expf(lg[k] - m); den += e[k]; }
    float inv = 1.0f / den;
    for (int k = 0; k < KEXP; ++k) aout[b * KEXP + k] = e[k] * inv;
  }
}

// ---------------------------------------------------------------------------
// Pass 3 (v3): Wdyn[b][cout][kk] bf16, kk = khw*128 + cin. One block of 512
// threads per cout. Stride-9 LDS reads = 2/bank = free; coalesced stores.
// ---------------------------------------------------------------------------
__global__ __launch_bounds__(512) void k_wdyn(const float* __restrict__ aout,
                                              const float* __restrict__ bank,
                                              unsigned short* __restrict__ wdyn) {
  const int cout = blockIdx.x, tid = threadIdx.x;
  __shared__ float4 bS4[KEXP * 288];          // 36 KB
  __shared__ float aS[B_ * KEXP];             // 256 routing coeffs

  for (int idx = tid; idx < KEXP * 288; idx += 512) {
    int k = idx / 288, r = idx - k * 288;
    bS4[idx] = ((const float4*)(bank + (size_t)(k * COUT + cout) * KK))[r];
  }
  if (tid < 256) aS[tid] = aout[tid];
  __syncthreads();

  const float* bS = (const float*)bS4;
  const int lane_kk = tid & 63;
  const int sg = tid >> 6;                    // 8 groups of 4 samples
  float areg[4][KEXP];
#pragma unroll
  for (int bi = 0; bi < 4; ++bi)
#pragma unroll
    for (int k = 0; k < KEXP; ++k) areg[bi][k] = aS[(sg * 4 + bi) * KEXP + k];

  for (int it = 0; it < 18; ++it) {
    int kk  = it * 64 + lane_kk;              // [0,1152)
    int khw = kk >> 7, cin = kk & 127;
    int e   = cin * 9 + khw;
    float vv[KEXP];
#pragma unroll
    for (int k = 0; k < KEXP; ++k) vv[k] = bS[k * KK + e];
#pragma unroll
    for (int bi = 0; bi < 4; ++bi) {
      float s = 0.f;
#pragma unroll
      for (int k = 0; k < KEXP; ++k) s += areg[bi][k] * vv[k];
      wdyn[(size_t)((sg * 4 + bi) * COUT + cout) * KK + kk] = f2bf(s);
    }
  }
}

// ---------------------------------------------------------------------------
// Pass 4 (R9): 256x256 MFMA GEMM per sample, overlap-tuned schedule.
//   Per K-tile: P0 split-quadrant (0,0) with af0 split-load; P1 (0,1) with
//   af(MH1) reload inside the MFMA slot; P2+P3 merged (1,1)+(1,0), both B
//   stages issued there. 5 barriers/tile. Counted vmcnt(2) at the switch
//   only (vmcnt(0) at prologue + final tile).
// ---------------------------------------------------------------------------
#define BARX()   asm volatile("s_barrier" ::: "memory")
#define WAITV2() asm volatile("s_waitcnt vmcnt(2)" ::: "memory")
#define WAITV0() asm volatile("s_waitcnt vmcnt(0)" ::: "memory")
#define SCHEDB() __builtin_amdgcn_sched_barrier(0)

__device__ __forceinline__ void stage_a(const unsigned short* wb, unsigned short* Abuf,
                                        int hf, int ad, const int (&aoffj)[2], int wv) {
  const unsigned short* s = wb + hf * 128 * KK + ad;
  unsigned short* d = Abuf + hf * 8192;
  gl_lds16(s + aoffj[0], d + (wv * 64) * 8);
  gl_lds16(s + aoffj[1], d + (512 + wv * 64) * 8);
}

__device__ __forceinline__ void stage_b(const unsigned short* xb, unsigned short* Bbuf,
                                        int hf, int bd, const int (&boffj)[2][2], int wv) {
  unsigned short* d = Bbuf + hf * 8192;
  gl_lds16(xb + boffj[0][hf] + bd, d + (wv * 64) * 8);
  gl_lds16(xb + boffj[1][hf] + bd, d + (512 + wv * 64) * 8);
}

template <int MH>
__device__ __forceinline__ void load_a(const unsigned short* Ab, int abase, int pA, int pB,
                                       v8bf (&af)[4][2]) {
#pragma unroll
  for (int mi = 0; mi < 4; ++mi) {
    int r = abase + (MH * 4 + mi) * 1024;
    af[mi][0] = *(const v8bf*)(Ab + r + pA);
    af[mi][1] = *(const v8bf*)(Ab + r + pB);
  }
}

template <int MH, int HALF>
__device__ __forceinline__ void load_a_half(const unsigned short* Ab, int abase,
                                            int pA, int pB, v8bf (&af)[4][2]) {
#pragma unroll
  for (int mi = HALF * 2; mi < HALF * 2 + 2; ++mi) {
    int r = abase + (MH * 4 + mi) * 1024;
    af[mi][0] = *(const v8bf*)(Ab + r + pA);
    af[mi][1] = *(const v8bf*)(Ab + r + pB);
  }
}

template <int NH>
__device__ __forceinline__ void load_b(const unsigned short* Bb, int bbase, int pA, int pB,
                                       v8bf (&bv)[2][2]) {
#pragma unroll
  for (int ni = 0; ni < 2; ++ni) {
    int r = bbase + (NH * 2 + ni) * 1024;
    bv[ni][0] = *(const v8bf*)(Bb + r + pA);
    bv[ni][1] = *(const v8bf*)(Bb + r + pB);
  }
}

// 8 MFMA: mi in {HALF*2, HALF*2+1}, ni 0..1, both k-slices (per-acc order
// identical to the full quadrant version -> bitwise-identical results).
template <int MH, int NH, int HALF>
__device__ __forceinline__ void mfma_h(v8bf (&af)[4][2], v8bf (&bv)[2][2],
                                       v4f (&acc)[8][4]) {
  __builtin_amdgcn_s_setprio(1);
#pragma unroll
  for (int mi = HALF * 2; mi < HALF * 2 + 2; ++mi)
#pragma unroll
    for (int ni = 0; ni < 2; ++ni) {
      v4f& a = acc[MH * 4 + mi][NH * 2 + ni];
      a = __builtin_amdgcn_mfma_f32_16x16x32_bf16(af[mi][0], bv[ni][0], a, 0, 0, 0);
      a = __builtin_amdgcn_mfma_f32_16x16x32_bf16(af[mi][1], bv[ni][1], a, 0, 0, 0);
    }
  __builtin_amdgcn_s_setprio(0);
}

template <int MH, int NH>
__device__ __forceinline__ void mfma_q(v8bf (&af)[4][2], v8bf (&bv)[2][2],
                                       v4f (&acc)[8][4]) {
  mfma_h<MH, NH, 0>(af, bv, acc);
  mfma_h<MH, NH, 1>(af, bv, acc);
}

__global__ __launch_bounds__(512, 2) void k_conv256(const unsigned short* __restrict__ wdyn,
                                                    const unsigned short* __restrict__ xpt,
                                                    float* __restrict__ out) {
  extern __shared__ unsigned short sh[];
  unsigned short* As = sh;             // [2][16384] ushorts (64 KB)
  unsigned short* Bs = sh + 32768;     // [2][16384] ushorts (64 KB)

  // T1: sample->XCD affinity. 416 = 8 XCDs * 52; XCD x owns samples 4x..4x+3,
  // sample-major so one sample's 13 chunks co-run on one XCD (wdyn[b] L2-hot).
  const int id  = blockIdx.x;
  const int xcd = id & 7, idx = id >> 3;         // 52 blocks per XCD
  const int b   = xcd * 4 + idx / 13;
  const int ch  = idx - (idx / 13) * 13;         // 13 pixel chunks of 256
  const int p0  = ch << 8;

  const int tid = threadIdx.x;
  const int wv = tid >> 6, l = tid & 63;
  const int q4 = l >> 4, l15 = l & 15;
  const int wr = wv >> 2, wc = wv & 3;           // 2M x 4N wave grid

  const unsigned short* wb = wdyn + (size_t)b * COUT * KK;
  const unsigned short* xb = xpt + (size_t)b * HP * WP * CIN;

  // Per-lane staging source offsets (ushort units), K-tile-invariant.
  int aoffj[2];
  int boffj[2][2];
#pragma unroll
  for (int j = 0; j < 2; ++j) {
    int row0 = j * 64 + (tid >> 3);              // [0,128) row within half-tile
    int c = (tid & 7) ^ (row0 & 7);              // pre-swizzled logical chunk
    aoffj[j] = row0 * KK + c * 8;
#pragma unroll
    for (int hf = 0; hf < 2; ++hf) {
      int p = p0 + hf * 128 + row0;
      p = p > 3135 ? 3135 : p;                   // clamp (tail chunk)
      int ph = p / 56, pw = p - ph * 56;
      boffj[j][hf] = (ph * WP + pw) * CIN + c * 8;
    }
  }

  // LDS read bases (ushort units).
  const int abase = (wr * 128 + l15) * 64;
  const int bbase = (wc * 64 + l15) * 64;
  const int s7 = l15 & 7;
  const int pA = (q4 ^ s7) * 8;                  // k-slice 0 phys chunk
  const int pB = ((q4 + 4) ^ s7) * 8;            // k-slice 1 phys chunk

  v4f acc[8][4];
#pragma unroll
  for (int m = 0; m < 8; ++m)
#pragma unroll
    for (int n = 0; n < 4; ++n)
#pragma unroll
      for (int rr = 0; rr < 4; ++rr) acc[m][n][rr] = 0.f;

  unsigned short* A0 = As;           unsigned short* B0 = Bs;
  unsigned short* A1 = As + 16384;   unsigned short* B1 = Bs + 16384;

  // Prologue: stage K-tile 0 (khw=0 -> bd=0, ad=0) into buf0, full drain once.
  stage_a(wb, A0, 0, 0, aoffj, wv);
  stage_a(wb, A0, 1, 0, aoffj, wv);
  stage_b(xb, B0, 0, 0, boffj, wv);
  stage_b(xb, B0, 1, 0, boffj, wv);
  WAITV0();
  BARX();

  v8bf afA[4][2], bv0[2][2], bv1[2][2];

  // One K-tile on (Ab,Bb); stage next tile into (An,Bn) when doStage.
  // Stage issue points: P0 A-h0, P1 A-h1, P2 B-h0+B-h1 (8 loads/wave/tile).
  auto halftile = [&](const unsigned short* Ab, const unsigned short* Bb,
                      unsigned short* An, unsigned short* Bn,
                      int adS, int bdS, bool doStage) {
    // P0 (switch): stage A h0, counted wait, barrier; split quadrant (0,0) so
    // the first 8 MFMA wait on only 8 reads.
    if (doStage) { stage_a(wb, An, 0, adS, aoffj, wv); WAITV2(); }
    else         { WAITV0(); }
    BARX();
    load_a_half<0, 0>(Ab, abase, pA, pB, afA);
    load_b<0>(Bb, bbase, pA, pB, bv0);
    mfma_h<0, 0, 0>(afA, bv0, acc);
    SCHEDB();
    load_a_half<0, 1>(Ab, abase, pA, pB, afA);
    mfma_h<0, 0, 1>(afA, bv0, acc);
    BARX();
    // P1: bv1 pre-issued with stage A h1; (0,1); af(MH1) reload inside the
    // MFMA slot (sched_barrier pins it after the mfma issue -> no reg growth).
    load_b<1>(Bb, bbase, pA, pB, bv1);
    if (doStage) stage_a(wb, An, 1, adS, aoffj, wv);
    BARX();
    mfma_h<0, 1, 0>(afA, bv1, acc);
    mfma_h<0, 1, 1>(afA, bv1, acc);
    SCHEDB();
    load_a<1>(Ab, abase, pA, pB, afA);
    BARX();
    // P2+P3 merged: both B stages issue, then (1,1) and (1,0) back-to-back.
    if (doStage) {
      stage_b(xb, Bn, 0, bdS, boffj, wv);
      stage_b(xb, Bn, 1, bdS, boffj, wv);
    }
    mfma_q<1, 1>(afA, bv1, acc);
    mfma_q<1, 0>(afA, bv0, acc);
    BARX();
  };

  int kh = 0, kw = 0;                            // khw = i for tiles 2i, 2i+1
  for (int i = 0; i < 9; ++i) {
    int kw2 = kw + 1, kh2 = kh;
    if (kw2 == 3) { kw2 = 0; kh2 = kh + 1; }     // khw = i+1 (next even tile)
    const int adO = (2 * i + 1) * 64;            // A k-offset, odd tile
    const int adN = (2 * i + 2) * 64;            // A k-offset, next even tile
    const int bdO = (kh * WP + kw) * CIN + 64;   // B disp, odd tile (cinb=64)
    const int bdN = (kh2 * WP + kw2) * CIN;      // B disp, next even (cinb=0)

    // compute buf0 (tile 2i), stage tile 2i+1 -> buf1
    halftile(A0, B0, A1, B1, adO, bdO, true);
    // compute buf1 (tile 2i+1), stage tile 2i+2 -> buf0 (not on last)
    halftile(A1, B1, A0, B0, adN, bdN, i != 8);

    kh = kh2; kw = kw2;
  }

  // Epilogue: D col = pixel (lane&15), D rows = cout = wr*128 + mf*16 + 4q + rr.
#pragma unroll
  for (int mf = 0; mf < 8; ++mf) {
    int cout = wr * 128 + mf * 16 + 4 * q4;
#pragma unroll
    for (int nf = 0; nf < 4; ++nf) {
      int p = p0 + wc * 64 + nf * 16 + l15;
      if (p < HW) {
        float* op = out + (size_t)(b * COUT + cout) * HW + p;
#pragma unroll
        for (int rr = 0; rr < 4; ++rr) op[(size_t)rr * HW] = acc[mf][nf][rr];
      }
    }
  }
}

// ---------------------------------------------------------------------------
// Workspace layout (~48.5 MB, all regions fully written before read):
//   [0, 917504)            gpart f32 [56][32][128]
//   [1 MB, +1024)          a f32 [32][8]
//   [2 MB, +18874368)      Wdyn bf16 [b][cout][1152]
//   [2MB+18874368, +27553792)  xp_t bf16 [b][58][58][128]
// ---------------------------------------------------------------------------
extern "C" void kernel_launch(void* const* d_in, const int* in_sizes, int n_in,
                              void* d_out, int out_size, void* d_ws, size_t ws_size,
                              hipStream_t stream) {
  const float* x    = (const float*)d_in[0];
  const float* bank = (const float*)d_in[1];
  const float* fc1w = (const float*)d_in[2];
  const float* fc1b = (const float*)d_in[3];
  const float* fc2w = (const float*)d_in[4];
  const float* fc2b = (const float*)d_in[5];
  float* out = (float*)d_out;

  char* ws = (char*)d_ws;
  float* gpart = (float*)(ws + 0);
  float* aout  = (float*)(ws + (1u << 20));
  unsigned short* wdyn = (unsigned short*)(ws + (2u << 20));
  unsigned short* xpt  = (unsigned short*)(ws + (2u << 20) + 18874368);

  static bool attr_done = false;
  if (!attr_done) {
    (void)hipFuncSetAttribute((const void*)k_conv256,
                              hipFuncAttributeMaxDynamicSharedMemorySize, 131072);
    attr_done = true;
  }

  k_xpose<<<dim3(H_, B_), 256, 0, stream>>>(x, xpt, gpart);
  k_mlp<<<dim3(B_), 128, 0, stream>>>(gpart, fc1w, fc1b, fc2w, fc2b, aout);
  k_wdyn<<<dim3(COUT), 512, 0, stream>>>(aout, bank, wdyn);
  k_conv256<<<dim3(416), 512, 131072, stream>>>(wdyn, xpt, out);
}

// Round 5
// 223.443 us; speedup vs baseline: 1.0762x; 1.0182x over previous
//
#include <hip/hip_runtime.h>

// DynamicConv2d: GAP->MLP->softmax routing, Wdyn = sum_k a_k * bank_k,
// then per-sample 3x3 conv (pad 1) = per-sample GEMM M=256,N=3136,K=1152.
// R10: k_conv re-tiled 256x256 -> 128x128 / 256 thr / 64KB LDS so TWO blocks
// co-reside per CU. Diagnosis: R9 measured 5100 cyc/tile vs 2480 MFMA floor
// with 1 block/CU — all waves barrier-locked in the same phase, latency
// fully exposed; plus 416 blocks = 2 dispatch rounds (19% tail). Two
// independent phase-offset blocks/CU hide each other's vmcnt/lgkmcnt/barrier
// stalls; 1600 blocks -> 3.125 fill rounds (~3% tail). Keeps R6's proven
// switch order (stage->vmcnt->barrier->read), R8's zig-zag fragment reuse,
// 2 barriers/tile, XCD sample affinity. Numerics (per-output K order)
// unchanged. Aux passes unchanged.

#define CIN    128
#define COUT   256
#define KEXP   8
#define HIDDEN 32
#define B_     32
#define H_     56
#define W_     56
#define HW     3136
#define HP     58      // 1 + 56 + 1 halo rows
#define WP     58      // 1 + 56 + 1 halo cols
#define KK     1152    // 9 * 128, order (kh*3+kw)*128 + cin

typedef float  v4f  __attribute__((ext_vector_type(4)));
typedef __bf16 v8bf __attribute__((ext_vector_type(8)));

__device__ __forceinline__ unsigned short f2bf(float x) {
  unsigned int u = __float_as_uint(x);
  u += 0x7fff + ((u >> 16) & 1);          // RNE
  return (unsigned short)(u >> 16);
}

// 16B-per-lane async global->LDS. LDS dest is wave-uniform base + lane*16.
__device__ __forceinline__ void gl_lds16(const void* g, void* lds) {
  __builtin_amdgcn_global_load_lds(
      (__attribute__((address_space(1))) void*)(unsigned long long)(g),
      (__attribute__((address_space(3))) void*)(lds),
      16, 0, 0);
}

// ---------------------------------------------------------------------------
// Pass 1 (v4): x (NCHW f32) -> xp_t (padded NHWC bf16, WP=58) + GAP partials
// to gpart[h][b][c] (no atomics). Blocks also zero their own halo cells.
// ---------------------------------------------------------------------------
__global__ __launch_bounds__(256) void k_xpose(const float* __restrict__ x,
                                               unsigned short* __restrict__ xpt,
                                               float* __restrict__ gpart) {
  const int h = blockIdx.x, b = blockIdx.y, tid = threadIdx.x;
  __shared__ float tf[56 * 129];      // 28.9 KB
  __shared__ float gp[256];
  const float4* xr4 = (const float4*)x + (size_t)b * CIN * 784;  // 784=3136/4

#pragma unroll
  for (int it = 0; it < 7; ++it) {    // 1792 float4 = 128c * 14wq
    int idx = it * 256 + tid;
    int c  = idx / 14;
    int wq = idx - c * 14;
    float4 q = xr4[(size_t)c * 784 + h * 14 + wq];
    int w0 = wq * 4;
    tf[(w0 + 0) * 129 + c] = q.x;
    tf[(w0 + 1) * 129 + c] = q.y;
    tf[(w0 + 2) * 129 + c] = q.z;
    tf[(w0 + 3) * 129 + c] = q.w;
  }
  __syncthreads();

  {                                   // GAP partial: 256 threads, 28 reads each
    int c = tid & 127, half = tid >> 7;
    float s = 0.f;
#pragma unroll
    for (int w = half * 28; w < half * 28 + 28; ++w) s += tf[w * 129 + c];
    gp[tid] = s;
  }

#pragma unroll
  for (int it = 0; it < 7; ++it) {    // 1792 ushort4 stores = 56w * 32 c-quads
    int idx = it * 256 + tid;
    int w  = idx >> 5;                // [0,56)
    int c4 = (idx & 31) << 2;         // [0,128) step 4
    ushort4 o;
    o.x = f2bf(tf[w * 129 + c4 + 0]);
    o.y = f2bf(tf[w * 129 + c4 + 1]);
    o.z = f2bf(tf[w * 129 + c4 + 2]);
    o.w = f2bf(tf[w * 129 + c4 + 3]);
    *(ushort4*)(xpt + ((size_t)(b * HP + (h + 1)) * WP + (w + 1)) * CIN + c4) = o;
  }

  // halo columns 0 and 57 of this image row
  if (tid < 128) {
    size_t rb = (size_t)(b * HP + (h + 1)) * WP * CIN;
    xpt[rb + tid] = 0;
    xpt[rb + 57 * CIN + tid] = 0;
  }
  // halo rows 0 and 57 (full 58*128 ushorts each)
  if (h == 0 || h == 55) {
    int hr = (h == 0) ? 0 : 57;
    size_t rb = (size_t)(b * HP + hr) * WP * CIN;
    ushort4 z; z.x = z.y = z.z = z.w = 0;
    for (int i = tid; i < 1856; i += 256)
      *(ushort4*)(xpt + rb + i * 4) = z;
  }

  __syncthreads();
  if (tid < 128)
    gpart[((size_t)h * B_ + b) * CIN + tid] =
        (gp[tid] + gp[tid + 128]) * (1.0f / 3136.0f);
}

// ---------------------------------------------------------------------------
// Pass 2 (v2): reduce gpart -> v (in LDS), then MLP + softmax. grid=32,
// block=128.
// ---------------------------------------------------------------------------
__global__ void k_mlp(const float* __restrict__ gpart, const float* __restrict__ fc1w,
                      const float* __restrict__ fc1b, const float* __restrict__ fc2w,
                      const float* __restrict__ fc2b, float* __restrict__ aout) {
  const int b = blockIdx.x, t = threadIdx.x;
  __shared__ float vS[CIN];
  __shared__ float hid[HIDDEN];
  __shared__ float lg[KEXP];
  {
    float s = 0.f;
    for (int h = 0; h < H_; ++h) s += gpart[((size_t)h * B_ + b) * CIN + t];
    vS[t] = s;
  }
  __syncthreads();
  if (t < HIDDEN) {
    float s = fc1b[t];
    const float* wr = fc1w + t * CIN;
    for (int c = 0; c < CIN; ++c) s += vS[c] * wr[c];
    hid[t] = fmaxf(s, 0.f);
  }
  __syncthreads();
  if (t < KEXP) {
    float s = fc2b[t];
    const float* wr = fc2w + t * HIDDEN;
    for (int j = 0; j < HIDDEN; ++j) s += hid[j] * wr[j];
    lg[t] = s;
  }
  __syncthreads();
  if (t == 0) {
    float m = lg[0];
    for (int k = 1; k < KEXP; ++k) m = fmaxf(m, lg[k]);
    float e[KEXP], den = 0.f;
    for (int k = 0; k < KEXP; ++k) { e[k] = expf(lg[k] - m); den += e[k]; }
    float inv = 1.0f / den;
    for (int k = 0; k < KEXP; ++k) aout[b * KEXP + k] = e[k] * inv;
  }
}

// ---------------------------------------------------------------------------
// Pass 3 (v3): Wdyn[b][cout][kk] bf16, kk = khw*128 + cin. One block of 512
// threads per cout. Stride-9 LDS reads = 2/bank = free; coalesced stores.
// ---------------------------------------------------------------------------
__global__ __launch_bounds__(512) void k_wdyn(const float* __restrict__ aout,
                                              const float* __restrict__ bank,
                                              unsigned short* __restrict__ wdyn) {
  const int cout = blockIdx.x, tid = threadIdx.x;
  __shared__ float4 bS4[KEXP * 288];          // 36 KB
  __shared__ float aS[B_ * KEXP];             // 256 routing coeffs

  for (int idx = tid; idx < KEXP * 288; idx += 512) {
    int k = idx / 288, r = idx - k * 288;
    bS4[idx] = ((const float4*)(bank + (size_t)(k * COUT + cout) * KK))[r];
  }
  if (tid < 256) aS[tid] = aout[tid];
  __syncthreads();

  const float* bS = (const float*)bS4;
  const int lane_kk = tid & 63;
  const int sg = tid >> 6;                    // 8 groups of 4 samples
  float areg[4][KEXP];
#pragma unroll
  for (int bi = 0; bi < 4; ++bi)
#pragma unroll
    for (int k = 0; k < KEXP; ++k) areg[bi][k] = aS[(sg * 4 + bi) * KEXP + k];

  for (int it = 0; it < 18; ++it) {
    int kk  = it * 64 + lane_kk;              // [0,1152)
    int khw = kk >> 7, cin = kk & 127;
    int e   = cin * 9 + khw;
    float vv[KEXP];
#pragma unroll
    for (int k = 0; k < KEXP; ++k) vv[k] = bS[k * KK + e];
#pragma unroll
    for (int bi = 0; bi < 4; ++bi) {
      float s = 0.f;
#pragma unroll
      for (int k = 0; k < KEXP; ++k) s += areg[bi][k] * vv[k];
      wdyn[(size_t)((sg * 4 + bi) * COUT + cout) * KK + kk] = f2bf(s);
    }
  }
}

// ---------------------------------------------------------------------------
// Pass 4 (R10): 128x128 MFMA GEMM tiles, 256 thr / 4 waves (2x2, 64x64 each),
//   64 KB double-buffered LDS -> 2 blocks/CU. Per K-tile (BK=64): zig-zag
//   quadrants (0,0)->(0,1)->(1,1)->(1,0), af cached across the MH pair,
//   bv0/bv1 live across the tile: 16 ds_read_b128 + 8 gl_lds per thread.
//   2 barriers/tile; switch order stage_a -> vmcnt(4) -> barrier -> reads.
// ---------------------------------------------------------------------------
#define BARX()   asm volatile("s_barrier" ::: "memory")
#define WAITV4() asm volatile("s_waitcnt vmcnt(4)" ::: "memory")
#define WAITV0() asm volatile("s_waitcnt vmcnt(0)" ::: "memory")

// Stage one 16 KB half-matrix tile (128 rows x 64 k, bf16) with 4 gl_lds16
// per thread. Source offsets pre-swizzled; LDS dest linear.
__device__ __forceinline__ void stage4(const unsigned short* src, unsigned short* dbuf,
                                       const int (&off)[4], int disp, int tid) {
#pragma unroll
  for (int g = 0; g < 4; ++g)
    gl_lds16(src + off[g] + disp, dbuf + (g * 256 + tid) * 8);
}

template <int MH>
__device__ __forceinline__ void load_a(const unsigned short* Ab, int abase, int pA, int pB,
                                       v8bf (&af)[2][2]) {
#pragma unroll
  for (int mi = 0; mi < 2; ++mi) {
    int r = abase + (MH * 2 + mi) * 1024;
    af[mi][0] = *(const v8bf*)(Ab + r + pA);
    af[mi][1] = *(const v8bf*)(Ab + r + pB);
  }
}

template <int NH>
__device__ __forceinline__ void load_b(const unsigned short* Bb, int bbase, int pA, int pB,
                                       v8bf (&bv)[2][2]) {
#pragma unroll
  for (int ni = 0; ni < 2; ++ni) {
    int r = bbase + (NH * 2 + ni) * 1024;
    bv[ni][0] = *(const v8bf*)(Bb + r + pA);
    bv[ni][1] = *(const v8bf*)(Bb + r + pB);
  }
}

template <int MH, int NH>
__device__ __forceinline__ void mfma_q(v8bf (&af)[2][2], v8bf (&bv)[2][2],
                                       v4f (&acc)[4][4]) {
  __builtin_amdgcn_s_setprio(1);
#pragma unroll
  for (int mi = 0; mi < 2; ++mi)
#pragma unroll
    for (int ni = 0; ni < 2; ++ni) {
      v4f& a = acc[MH * 2 + mi][NH * 2 + ni];
      a = __builtin_amdgcn_mfma_f32_16x16x32_bf16(af[mi][0], bv[ni][0], a, 0, 0, 0);
      a = __builtin_amdgcn_mfma_f32_16x16x32_bf16(af[mi][1], bv[ni][1], a, 0, 0, 0);
    }
  __builtin_amdgcn_s_setprio(0);
}

__global__ __launch_bounds__(256, 2) void k_conv128(const unsigned short* __restrict__ wdyn,
                                                    const unsigned short* __restrict__ xpt,
                                                    float* __restrict__ out) {
  extern __shared__ unsigned short sh[];
  unsigned short* As = sh;             // [2][8192] ushorts (32 KB)
  unsigned short* Bs = sh + 16384;     // [2][8192] ushorts (32 KB)

  // T1: sample->XCD affinity. 1600 = 8 XCDs * (4 samples * 2 mtiles * 25 ch).
  // Within an XCD: 50 consecutive blocks share a sample (wdyn[b], xpt[b]
  // L2-hot); within those, 25 share an m-tile (A panel reuse).
  const int id  = blockIdx.x;
  const int xcd = id & 7, idx = id >> 3;         // idx 0..199
  const int bs  = idx / 50;
  const int r   = idx - bs * 50;
  const int b   = xcd * 4 + bs;
  const int bm  = r / 25;
  const int ch  = r - bm * 25;                   // 25 chunks of 128 pixels
  const int p0  = ch << 7;

  const int tid = threadIdx.x;
  const int wv = tid >> 6, l = tid & 63;
  const int q4 = l >> 4, l15 = l & 15;
  const int wr = wv >> 1, wc = wv & 1;           // 2M x 2N wave grid

  const unsigned short* wb = wdyn + ((size_t)b * COUT + bm * 128) * KK;
  const unsigned short* xb = xpt + (size_t)b * HP * WP * CIN;

  // Per-lane staging source offsets (ushort units), K-tile-invariant.
  // 16 KB half-tile = 1024 slots of 16B; 4 groups of 256 threads.
  int aoff[4], boff[4];
#pragma unroll
  for (int g = 0; g < 4; ++g) {
    int gidx = g * 256 + tid;                    // 0..1023
    int row = gidx >> 3;                         // 0..127
    int c = (gidx & 7) ^ (row & 7);              // pre-swizzled logical chunk
    aoff[g] = row * KK + c * 8;
    int p = p0 + row;
    p = p > 3135 ? 3135 : p;                     // clamp (tail chunk 24)
    int ph = p / 56, pw = p - ph * 56;
    boff[g] = (ph * WP + pw) * CIN + c * 8;
  }

  // LDS read bases (ushort units).
  const int abase = (wr * 64 + l15) * 64;
  const int bbase = (wc * 64 + l15) * 64;
  const int s7 = l15 & 7;
  const int pA = (q4 ^ s7) * 8;                  // k-slice 0 phys chunk
  const int pB = ((q4 + 4) ^ s7) * 8;            // k-slice 1 phys chunk

  v4f acc[4][4];
#pragma unroll
  for (int m = 0; m < 4; ++m)
#pragma unroll
    for (int n = 0; n < 4; ++n)
#pragma unroll
      for (int rr = 0; rr < 4; ++rr) acc[m][n][rr] = 0.f;

  unsigned short* A0 = As;          unsigned short* B0 = Bs;
  unsigned short* A1 = As + 8192;   unsigned short* B1 = Bs + 8192;

  // Prologue: stage K-tile 0 (khw=0 -> disp 0) into buf0, full drain once.
  stage4(wb, A0, aoff, 0, tid);
  stage4(xb, B0, boff, 0, tid);
  WAITV0();
  BARX();

  v8bf afA[2][2], bv0[2][2], bv1[2][2];

  // One K-tile on (Ab,Bb); stage next tile into (An,Bn) when doStage.
  // vmcnt: 8 outstanding from prev tile at P0; +4 A-stages -> wait(4) drains
  // exactly the prev 8. 2 barriers per tile; buffer being restaged was last
  // read a full tile ago (before the previous end-barrier) -> WAR safe.
  auto tile = [&](const unsigned short* Ab, const unsigned short* Bb,
                  unsigned short* An, unsigned short* Bn,
                  int adS, int bdS, bool doStage) {
    if (doStage) { stage4(wb, An, aoff, adS, tid); WAITV4(); }
    else         { WAITV0(); }
    BARX();
    load_a<0>(Ab, abase, pA, pB, afA);
    load_b<0>(Bb, bbase, pA, pB, bv0);
    mfma_q<0, 0>(afA, bv0, acc);
    load_b<1>(Bb, bbase, pA, pB, bv1);
    if (doStage) stage4(xb, Bn, boff, bdS, tid);
    mfma_q<0, 1>(afA, bv1, acc);
    load_a<1>(Ab, abase, pA, pB, afA);
    mfma_q<1, 1>(afA, bv1, acc);
    mfma_q<1, 0>(afA, bv0, acc);
    BARX();
  };

  int kh = 0, kw = 0;                            // khw = i for tiles 2i, 2i+1
  for (int i = 0; i < 9; ++i) {
    int kw2 = kw + 1, kh2 = kh;
    if (kw2 == 3) { kw2 = 0; kh2 = kh + 1; }     // khw = i+1 (next even tile)
    const int adO = (2 * i + 1) * 64;            // A k-offset, odd tile
    const int adN = (2 * i + 2) * 64;            // A k-offset, next even tile
    const int bdO = (kh * WP + kw) * CIN + 64;   // B disp, odd tile (cinb=64)
    const int bdN = (kh2 * WP + kw2) * CIN;      // B disp, next even (cinb=0)

    tile(A0, B0, A1, B1, adO, bdO, true);        // compute 2i, stage 2i+1
    tile(A1, B1, A0, B0, adN, bdN, i != 8);      // compute 2i+1, stage 2i+2

    kh = kh2; kw = kw2;
  }

  // Epilogue: D col = pixel (lane&15), D rows = cout.
#pragma unroll
  for (int mf = 0; mf < 4; ++mf) {
    int cout = bm * 128 + wr * 64 + mf * 16 + 4 * q4;
#pragma unroll
    for (int nf = 0; nf < 4; ++nf) {
      int p = p0 + wc * 64 + nf * 16 + l15;
      if (p < HW) {
        float* op = out + (size_t)(b * COUT + cout) * HW + p;
#pragma unroll
        for (int rr = 0; rr < 4; ++rr) op[(size_t)rr * HW] = acc[mf][nf][rr];
      }
    }
  }
}

// ---------------------------------------------------------------------------
// Workspace layout (~48.5 MB, all regions fully written before read):
//   [0, 917504)            gpart f32 [56][32][128]
//   [1 MB, +1024)          a f32 [32][8]
//   [2 MB, +18874368)      Wdyn bf16 [b][cout][1152]
//   [2MB+18874368, +27553792)  xp_t bf16 [b][58][58][128]
// ---------------------------------------------------------------------------
extern "C" void kernel_launch(void* const* d_in, const int* in_sizes, int n_in,
                              void* d_out, int out_size, void* d_ws, size_t ws_size,
                              hipStream_t stream) {
  const float* x    = (const float*)d_in[0];
  const float* bank = (const float*)d_in[1];
  const float* fc1w = (const float*)d_in[2];
  const float* fc1b = (const float*)d_in[3];
  const float* fc2w = (const float*)d_in[4];
  const float* fc2b = (const float*)d_in[5];
  float* out = (float*)d_out;

  char* ws = (char*)d_ws;
  float* gpart = (float*)(ws + 0);
  float* aout  = (float*)(ws + (1u << 20));
  unsigned short* wdyn = (unsigned short*)(ws + (2u << 20));
  unsigned short* xpt  = (unsigned short*)(ws + (2u << 20) + 18874368);

  static bool attr_done = false;
  if (!attr_done) {
    (void)hipFuncSetAttribute((const void*)k_conv128,
                              hipFuncAttributeMaxDynamicSharedMemorySize, 65536);
    attr_done = true;
  }

  k_xpose<<<dim3(H_, B_), 256, 0, stream>>>(x, xpt, gpart);
  k_mlp<<<dim3(B_), 128, 0, stream>>>(gpart, fc1w, fc1b, fc2w, fc2b, aout);
  k_wdyn<<<dim3(COUT), 512, 0, stream>>>(aout, bank, wdyn);
  k_conv128<<<dim3(1600), 256, 65536, stream>>>(wdyn, xpt, out);
}